// Round 20
// baseline (199.617 us; speedup 1.0000x reference)
//
#include <hip/hip_runtime.h>
#include <hip/hip_bf16.h>
#include <math.h>

#define B_    8
#define C_    256
#define L_    4096
#define OCH_  256

typedef __attribute__((ext_vector_type(8)))  short bf16x8;
typedef __attribute__((ext_vector_type(16))) float f32x16;
typedef __attribute__((ext_vector_type(4)))  int   i32x4;

static __device__ __forceinline__ unsigned short bf16_rne(float f) {
    unsigned u = __float_as_uint(f);
    unsigned r = u + 0x7FFFu + ((u >> 16) & 1u);
    return (unsigned short)(r >> 16);
}

static __device__ __forceinline__ void gload_lds16(const void* g, void* l) {
    __builtin_amdgcn_global_load_lds(
        (const __attribute__((address_space(1))) unsigned int*)g,
        (__attribute__((address_space(3))) unsigned int*)l, 16, 0, 0);
}

// ---------------------------------------------------------------------------
// K1: offset network + fused weight split — LDS-staged x tile.
// Block 256 thr, grid B x (L/64). Stage x[b,0:256,l0:l0+64] (64 KB) into
// sX[c][l] via 16 rounds of global_load_lds w=16 (coalesced rows; LDS dst
// = wave-uniform base + lane*16). MLP reads xv from LDS (2-way alias, free).
// Layer-1 sum order = single c=0..63 (R16-proven numerics).
// coef[(b*3+t)*L + l] = { d0, d1, bits(i0f2), 0 }.
// ---------------------------------------------------------------------------
__global__ __launch_bounds__(256) void k_offsets(
        const float* __restrict__ x,
        const float* __restrict__ w1, const float* __restrict__ b1,
        const float* __restrict__ w2, const float* __restrict__ b2,
        const float* __restrict__ W,  unsigned short* __restrict__ Wb,
        float4* __restrict__ coef) {
    __shared__ float sX[C_ * 64];                    // 64 KB  [c][l]
    __shared__ float sOm[64][37];                    // 9.25 KB
    int tid  = threadIdx.x;
    int blk  = blockIdx.x;

    int b  = blk & 7;                                // XCD affinity
    int l0 = (blk >> 3) << 6;
    const float* xb = x + (size_t)b * C_ * L_;

    // ---- stage x tile: 16 rounds x 4KB, all coalesced ----
    {
        int rowi = tid >> 4;                         // 0..15
        int co   = (tid & 15) * 4;                   // element offset in row
        #pragma unroll
        for (int r = 0; r < 16; ++r) {
            int row = r * 16 + rowi;
            gload_lds16(xb + (size_t)row * L_ + l0 + co, &sX[row * 64 + co]);
        }
    }

    // ---- fused weight split: W[o][c][k] -> Wb[o][k*256+c], 384/block ----
    {
        int i = blk * 384 + tid;                     // o*768 + c*3 + k
        int k = i % 3;
        int c = (i / 3) & 255;
        int o = i / 768;
        Wb[o * 768 + k * 256 + c] = bf16_rne(W[i]);
        if (tid < 128) {
            int i2 = blk * 384 + 256 + tid;
            int k2 = i2 % 3;
            int c2 = (i2 / 3) & 255;
            int o2 = i2 / 768;
            Wb[o2 * 768 + k2 * 256 + c2] = bf16_rne(W[i2]);
        }
    }
    __syncthreads();                                 // drains vmcnt + barrier

    int l = tid & 63;
    int g = tid >> 6;

    // ---- layer 1: h = W1_g · x[g*64 .. g*64+63][l] + b1 (from LDS) ----
    const float* w1g = w1 + (g * 16) * 64;
    const float* xs  = sX + (g * 64) * 64 + l;
    float h[16];
    #pragma unroll
    for (int o = 0; o < 16; ++o) h[o] = b1[g * 16 + o];
    #pragma unroll
    for (int c = 0; c < 64; ++c) {
        float xv = xs[c * 64];
        #pragma unroll
        for (int o = 0; o < 16; ++o) h[o] = fmaf(xv, w1g[o * 64 + c], h[o]);
    }

    // ---- layer 2: om9 = W2_g · gelu(h) + b2 ----
    float om9[9];
    #pragma unroll
    for (int j = 0; j < 9; ++j) om9[j] = b2[g * 9 + j];
    #pragma unroll
    for (int o = 0; o < 16; ++o) {
        float a  = h[o];
        float hv = 0.5f * a * (1.0f + erff(a * 0.70710678118654752f));
        const float* w2p = w2 + g * 144 + o;         // w2[g][j][o]
        #pragma unroll
        for (int j = 0; j < 9; ++j) om9[j] = fmaf(hv, w2p[j * 16], om9[j]);
    }
    #pragma unroll
    for (int j = 0; j < 9; ++j) sOm[l][g * 9 + j] = om9[j];
    __syncthreads();
    if (tid >= 64) return;

    // ---- softmax over channels 3..35, window-form coef ----
    float om[36];
    #pragma unroll
    for (int j = 0; j < 36; ++j) om[j] = sOm[tid][j];
    om[1] = 0.0f; om[3] = 0.0f; om[5] = 0.0f;
    float m = om[3];
    #pragma unroll
    for (int j = 4; j < 36; ++j) m = fmaxf(m, om[j]);
    float ssum = 0.0f;
    #pragma unroll
    for (int j = 3; j < 36; ++j) ssum += expf(om[j] - m);
    float inv = 1.0f / ssum;

    int lpos = l0 + tid;
    float base = -1.0f + 2.0f * (float)lpos / (float)(L_ - 1);
    #pragma unroll
    for (int t = 0; t < 3; ++t) {
        float mod  = expf(om[3 + t] - m) * inv;
        float off  = om[2 * t] * (2.0f / (float)L_);
        float grid = base + (-0.5f + 0.5f * (float)t) + off;
        float pp   = (grid + 1.0f) * 0.5f * (float)(L_ - 1);
        float fp   = floorf(pp);
        int i0 = (int)fp, i1 = i0 + 1;
        float w = pp - fp;
        float c0 = (i0 >= 0 && i0 < L_) ? (1.0f - w) * mod : 0.0f;
        float c1 = (i1 >= 0 && i1 < L_) ? w * mod : 0.0f;
        int i0c  = min(max(i0, 0), L_ - 1);
        int i1c  = min(max(i1, 0), L_ - 1);
        int i0f2 = min(max(i0, 0), L_ - 2);
        float d0 = (i0c == i0f2     ? c0 : 0.0f) + (i1c == i0f2     ? c1 : 0.0f);
        float d1 = (i0c == i0f2 + 1 ? c0 : 0.0f) + (i1c == i0f2 + 1 ? c1 : 0.0f);
        coef[((size_t)b * 3 + t) * L_ + lpos] =
            make_float4(d0, d1, __int_as_float(i0f2), 0.0f);
    }
}

// ---------------------------------------------------------------------------
// K2: FUSED sample + 1-pass bf16 MFMA GEMM (R15-proven, byte-identical).
// Tile 256o x 128l, grid 256. Per chunk: issue A(ch+1)+G(ch+1) ->
// 16 MFMAs (gathers fly underneath) -> pack -> ds_write buf^1 -> sync.
// ---------------------------------------------------------------------------
__global__ __launch_bounds__(512, 2) void k_conv(
        const float* __restrict__ x,
        const unsigned short* __restrict__ Wb,
        const float* __restrict__ bias,
        const float4* __restrict__ coef,
        float* __restrict__ out) {
    __shared__ i32x4 sS[2][8][128];                  // 32 KB

    const int tid  = threadIdx.x;
    const int lane = tid & 63;
    const int wv   = tid >> 6;                       // 0..7
    const int blk  = blockIdx.x;
    const int b    = blk & 7;                        // XCD affinity
    const int lt   = blk >> 3;                       // 0..31
    const int l0   = lt * 128;
    const int q    = lane >> 5;
    const int l31  = lane & 31;
    const int ls   = tid & 127;                      // staging column
    const int su   = tid >> 7;                       // staging sub-slot 0..3

    const float* xb = x + (size_t)b * (C_ * L_);

    float4 cf0 = coef[((size_t)b * 3 + 0) * L_ + l0 + ls];
    float4 cf1 = coef[((size_t)b * 3 + 1) * L_ + l0 + ls];
    float4 cf2 = coef[((size_t)b * 3 + 2) * L_ + l0 + ls];
    const int   ib0 = __float_as_int(cf0.z), ib1 = __float_as_int(cf1.z), ib2 = __float_as_int(cf2.z);
    const float d00 = cf0.x, d01 = cf0.y;
    const float d10 = cf1.x, d11 = cf1.y;
    const float d20 = cf2.x, d21 = cf2.y;

    const unsigned short* WA = Wb + (size_t)(wv * 32 + l31) * 768 + q * 8;

    f32x16 acc0, acc1, acc2, acc3;
    #pragma unroll
    for (int i = 0; i < 16; ++i) { acc0[i] = 0.f; acc1[i] = 0.f; acc2[i] = 0.f; acc3[i] = 0.f; }

    bf16x8 aP0, aP1, aP2, aP3, aQ0, aQ1, aQ2, aQ3;
    float g0a[8], g1a[8], g0b[8], g1b[8];
    float dA0, dA1, dB0, dB1;

    #define GATHER(CH, SL, G0, G1, D0, D1) {                                  \
        int s_   = (CH) * 8 + (SL);                                           \
        int tap_ = s_ >> 5;                                                   \
        int c0_  = s_ * 8 - tap_ * 256;                                       \
        int ib_  = tap_ == 2 ? ib2 : tap_ == 1 ? ib1 : ib0;                   \
        D0 = tap_ == 2 ? d20 : tap_ == 1 ? d10 : d00;                         \
        D1 = tap_ == 2 ? d21 : tap_ == 1 ? d11 : d01;                         \
        const float* xp_ = xb + (size_t)c0_ * L_ + ib_;                       \
        _Pragma("unroll")                                                     \
        for (int j = 0; j < 8; ++j) {                                         \
            G0[j] = xp_[(size_t)j * L_];                                      \
            G1[j] = xp_[(size_t)j * L_ + 1];                                  \
        }                                                                     \
    }
    #define PACK(NBUF, SL, G0, G1, D0, D1) {                                  \
        union { unsigned short us[8]; i32x4 v; } ph_;                         \
        _Pragma("unroll")                                                     \
        for (int e = 0; e < 8; ++e)                                           \
            ph_.us[e] = bf16_rne(fmaf(G1[e], D1, G0[e] * D0));                \
        sS[NBUF][SL][ls] = ph_.v;                                             \
    }

    aP0 = *(const bf16x8*)(WA);
    aP1 = *(const bf16x8*)(WA + 16);
    aP2 = *(const bf16x8*)(WA + 32);
    aP3 = *(const bf16x8*)(WA + 48);
    GATHER(0, su,     g0a, g1a, dA0, dA1)
    GATHER(0, su + 4, g0b, g1b, dB0, dB1)
    PACK(0, su,     g0a, g1a, dA0, dA1)
    PACK(0, su + 4, g0b, g1b, dB0, dB1)
    __syncthreads();

    #pragma unroll
    for (int ch = 0; ch < 12; ++ch) {
        const int buf = ch & 1;

        if (ch < 11) {
            const unsigned short* wn = WA + (ch + 1) * 64;
            aQ0 = *(const bf16x8*)(wn);
            aQ1 = *(const bf16x8*)(wn + 16);
            aQ2 = *(const bf16x8*)(wn + 32);
            aQ3 = *(const bf16x8*)(wn + 48);
            GATHER(ch + 1, su,     g0a, g1a, dA0, dA1)
            GATHER(ch + 1, su + 4, g0b, g1b, dB0, dB1)
        }
        __builtin_amdgcn_sched_barrier(0);

        #define KS_STEP(ks, AP) {                                            \
            const i32x4* bp = &sS[buf][(ks) * 2 + q][l31];                   \
            bf16x8 b0 = *(const bf16x8*)(bp);                                \
            bf16x8 b1 = *(const bf16x8*)(bp + 32);                           \
            bf16x8 b2 = *(const bf16x8*)(bp + 64);                           \
            bf16x8 b3 = *(const bf16x8*)(bp + 96);                           \
            __builtin_amdgcn_s_setprio(1);                                   \
            acc0 = __builtin_amdgcn_mfma_f32_32x32x16_bf16(AP, b0, acc0, 0, 0, 0); \
            acc1 = __builtin_amdgcn_mfma_f32_32x32x16_bf16(AP, b1, acc1, 0, 0, 0); \
            acc2 = __builtin_amdgcn_mfma_f32_32x32x16_bf16(AP, b2, acc2, 0, 0, 0); \
            acc3 = __builtin_amdgcn_mfma_f32_32x32x16_bf16(AP, b3, acc3, 0, 0, 0); \
            __builtin_amdgcn_s_setprio(0);                                   \
        }
        KS_STEP(0, aP0)
        KS_STEP(1, aP1)
        KS_STEP(2, aP2)
        KS_STEP(3, aP3)
        #undef KS_STEP
        __builtin_amdgcn_sched_barrier(0);

        if (ch < 11) {
            PACK(buf ^ 1, su,     g0a, g1a, dA0, dA1)
            PACK(buf ^ 1, su + 4, g0b, g1b, dB0, dB1)
            aP0 = aQ0; aP1 = aQ1; aP2 = aQ2; aP3 = aQ3;
        }
        __syncthreads();
    }
    #undef GATHER
    #undef PACK

    #pragma unroll
    for (int reg = 0; reg < 16; ++reg) {
        int rr = (reg & 3) + 8 * (reg >> 2) + 4 * q;
        int o  = wv * 32 + rr;
        float bv = bias[o];
        float* op = out + ((size_t)b * 256 + o) * L_ + l0 + l31;
        op[0]  = acc0[reg] + bv;
        op[32] = acc1[reg] + bv;
        op[64] = acc2[reg] + bv;
        op[96] = acc3[reg] + bv;
    }
}

// ---------------------------------------------------------------------------
extern "C" void kernel_launch(void* const* d_in, const int* in_sizes, int n_in,
                              void* d_out, int out_size, void* d_ws, size_t ws_size,
                              hipStream_t stream) {
    const float* x      = (const float*)d_in[0];
    const float* weight = (const float*)d_in[1];
    const float* bias   = (const float*)d_in[2];
    const float* w1     = (const float*)d_in[3];
    const float* b1     = (const float*)d_in[4];
    const float* w2     = (const float*)d_in[5];
    const float* b2     = (const float*)d_in[6];
    float* out = (float*)d_out;

    const size_t COEF_B = (size_t)B_ * 3 * L_ * sizeof(float4);   // 1.5 MB
    char* ws = (char*)d_ws;
    float4*         coef = (float4*)ws;
    unsigned short* Wb   = (unsigned short*)(ws + COEF_B);        // 384 KB

    k_offsets<<<B_ * (L_ / 64), 256, 0, stream>>>(x, w1, b1, w2, b2,
                                                  weight, Wb, coef);
    k_conv<<<B_ * (L_ / 128), 512, 0, stream>>>(x, Wb, bias, coef, out);
}

// Round 21
// 67.966 us; speedup vs baseline: 2.9370x; 2.9370x over previous
//
#include <hip/hip_runtime.h>
#include <hip/hip_bf16.h>
#include <math.h>

#define B_    8
#define C_    256
#define L_    4096
#define OCH_  256

typedef __attribute__((ext_vector_type(8)))  short bf16x8;
typedef __attribute__((ext_vector_type(16))) float f32x16;
typedef __attribute__((ext_vector_type(4)))  int   i32x4;

static __device__ __forceinline__ unsigned short bf16_rne(float f) {
    unsigned u = __float_as_uint(f);
    unsigned r = u + 0x7FFFu + ((u >> 16) & 1u);
    return (unsigned short)(r >> 16);
}

static __device__ __forceinline__ void gload_lds16(const void* g, void* l) {
    __builtin_amdgcn_global_load_lds(
        (const __attribute__((address_space(1))) unsigned int*)g,
        (__attribute__((address_space(3))) unsigned int*)l, 16, 0, 0);
}

// ---------------------------------------------------------------------------
// K1: offset network + fused weight split — LDS-staged x tile.
// Identical to R20 (passed, absmax 4.882812e-4) EXCEPT: c-loop is
// #pragma unroll 8 (R20's full unroll made the scheduler hoist all 64
// ds_reads + 1024 w1 loads -> VGPR 256 + 282 MB scratch spill).
// 8-deep chunks: 8 ds_reads in flight over 128 FMAs -> covers LDS latency
// with ~40 live VGPRs.
// ---------------------------------------------------------------------------
__global__ __launch_bounds__(256) void k_offsets(
        const float* __restrict__ x,
        const float* __restrict__ w1, const float* __restrict__ b1,
        const float* __restrict__ w2, const float* __restrict__ b2,
        const float* __restrict__ W,  unsigned short* __restrict__ Wb,
        float4* __restrict__ coef) {
    __shared__ float sX[C_ * 64];                    // 64 KB  [c][l]
    __shared__ float sOm[64][37];                    // 9.25 KB
    int tid  = threadIdx.x;
    int blk  = blockIdx.x;

    int b  = blk & 7;                                // XCD affinity
    int l0 = (blk >> 3) << 6;
    const float* xb = x + (size_t)b * C_ * L_;

    // ---- stage x tile: 16 rounds x 4KB, all coalesced ----
    {
        int rowi = tid >> 4;                         // 0..15
        int co   = (tid & 15) * 4;                   // element offset in row
        #pragma unroll
        for (int r = 0; r < 16; ++r) {
            int row = r * 16 + rowi;
            gload_lds16(xb + (size_t)row * L_ + l0 + co, &sX[row * 64 + co]);
        }
    }

    // ---- fused weight split: W[o][c][k] -> Wb[o][k*256+c], 384/block ----
    {
        int i = blk * 384 + tid;                     // o*768 + c*3 + k
        int k = i % 3;
        int c = (i / 3) & 255;
        int o = i / 768;
        Wb[o * 768 + k * 256 + c] = bf16_rne(W[i]);
        if (tid < 128) {
            int i2 = blk * 384 + 256 + tid;
            int k2 = i2 % 3;
            int c2 = (i2 / 3) & 255;
            int o2 = i2 / 768;
            Wb[o2 * 768 + k2 * 256 + c2] = bf16_rne(W[i2]);
        }
    }
    __syncthreads();                                 // drains vmcnt + barrier

    int l = tid & 63;
    int g = tid >> 6;

    // ---- layer 1: h = W1_g · x[g*64 .. +63][l] + b1 (LDS reads, unroll 8) ----
    const float* w1g = w1 + (g * 16) * 64;
    const float* xs  = sX + (g * 64) * 64 + l;
    float h[16];
    #pragma unroll
    for (int o = 0; o < 16; ++o) h[o] = b1[g * 16 + o];
    #pragma unroll 8
    for (int c = 0; c < 64; ++c) {
        float xv = xs[c * 64];
        #pragma unroll
        for (int o = 0; o < 16; ++o) h[o] = fmaf(xv, w1g[o * 64 + c], h[o]);
    }

    // ---- layer 2: om9 = W2_g · gelu(h) + b2 ----
    float om9[9];
    #pragma unroll
    for (int j = 0; j < 9; ++j) om9[j] = b2[g * 9 + j];
    #pragma unroll
    for (int o = 0; o < 16; ++o) {
        float a  = h[o];
        float hv = 0.5f * a * (1.0f + erff(a * 0.70710678118654752f));
        const float* w2p = w2 + g * 144 + o;         // w2[g][j][o]
        #pragma unroll
        for (int j = 0; j < 9; ++j) om9[j] = fmaf(hv, w2p[j * 16], om9[j]);
    }
    #pragma unroll
    for (int j = 0; j < 9; ++j) sOm[l][g * 9 + j] = om9[j];
    __syncthreads();
    if (tid >= 64) return;

    // ---- softmax over channels 3..35, window-form coef ----
    float om[36];
    #pragma unroll
    for (int j = 0; j < 36; ++j) om[j] = sOm[tid][j];
    om[1] = 0.0f; om[3] = 0.0f; om[5] = 0.0f;
    float m = om[3];
    #pragma unroll
    for (int j = 4; j < 36; ++j) m = fmaxf(m, om[j]);
    float ssum = 0.0f;
    #pragma unroll
    for (int j = 3; j < 36; ++j) ssum += expf(om[j] - m);
    float inv = 1.0f / ssum;

    int lpos = l0 + tid;
    float base = -1.0f + 2.0f * (float)lpos / (float)(L_ - 1);
    #pragma unroll
    for (int t = 0; t < 3; ++t) {
        float mod  = expf(om[3 + t] - m) * inv;
        float off  = om[2 * t] * (2.0f / (float)L_);
        float grid = base + (-0.5f + 0.5f * (float)t) + off;
        float pp   = (grid + 1.0f) * 0.5f * (float)(L_ - 1);
        float fp   = floorf(pp);
        int i0 = (int)fp, i1 = i0 + 1;
        float w = pp - fp;
        float c0 = (i0 >= 0 && i0 < L_) ? (1.0f - w) * mod : 0.0f;
        float c1 = (i1 >= 0 && i1 < L_) ? w * mod : 0.0f;
        int i0c  = min(max(i0, 0), L_ - 1);
        int i1c  = min(max(i1, 0), L_ - 1);
        int i0f2 = min(max(i0, 0), L_ - 2);
        float d0 = (i0c == i0f2     ? c0 : 0.0f) + (i1c == i0f2     ? c1 : 0.0f);
        float d1 = (i0c == i0f2 + 1 ? c0 : 0.0f) + (i1c == i0f2 + 1 ? c1 : 0.0f);
        coef[((size_t)b * 3 + t) * L_ + lpos] =
            make_float4(d0, d1, __int_as_float(i0f2), 0.0f);
    }
}

// ---------------------------------------------------------------------------
// K2: FUSED sample + 1-pass bf16 MFMA GEMM (R15-proven, byte-identical).
// Tile 256o x 128l, grid 256. Per chunk: issue A(ch+1)+G(ch+1) ->
// 16 MFMAs (gathers fly underneath) -> pack -> ds_write buf^1 -> sync.
// ---------------------------------------------------------------------------
__global__ __launch_bounds__(512, 2) void k_conv(
        const float* __restrict__ x,
        const unsigned short* __restrict__ Wb,
        const float* __restrict__ bias,
        const float4* __restrict__ coef,
        float* __restrict__ out) {
    __shared__ i32x4 sS[2][8][128];                  // 32 KB

    const int tid  = threadIdx.x;
    const int lane = tid & 63;
    const int wv   = tid >> 6;                       // 0..7
    const int blk  = blockIdx.x;
    const int b    = blk & 7;                        // XCD affinity
    const int lt   = blk >> 3;                       // 0..31
    const int l0   = lt * 128;
    const int q    = lane >> 5;
    const int l31  = lane & 31;
    const int ls   = tid & 127;                      // staging column
    const int su   = tid >> 7;                       // staging sub-slot 0..3

    const float* xb = x + (size_t)b * (C_ * L_);

    float4 cf0 = coef[((size_t)b * 3 + 0) * L_ + l0 + ls];
    float4 cf1 = coef[((size_t)b * 3 + 1) * L_ + l0 + ls];
    float4 cf2 = coef[((size_t)b * 3 + 2) * L_ + l0 + ls];
    const int   ib0 = __float_as_int(cf0.z), ib1 = __float_as_int(cf1.z), ib2 = __float_as_int(cf2.z);
    const float d00 = cf0.x, d01 = cf0.y;
    const float d10 = cf1.x, d11 = cf1.y;
    const float d20 = cf2.x, d21 = cf2.y;

    const unsigned short* WA = Wb + (size_t)(wv * 32 + l31) * 768 + q * 8;

    f32x16 acc0, acc1, acc2, acc3;
    #pragma unroll
    for (int i = 0; i < 16; ++i) { acc0[i] = 0.f; acc1[i] = 0.f; acc2[i] = 0.f; acc3[i] = 0.f; }

    bf16x8 aP0, aP1, aP2, aP3, aQ0, aQ1, aQ2, aQ3;
    float g0a[8], g1a[8], g0b[8], g1b[8];
    float dA0, dA1, dB0, dB1;

    #define GATHER(CH, SL, G0, G1, D0, D1) {                                  \
        int s_   = (CH) * 8 + (SL);                                           \
        int tap_ = s_ >> 5;                                                   \
        int c0_  = s_ * 8 - tap_ * 256;                                       \
        int ib_  = tap_ == 2 ? ib2 : tap_ == 1 ? ib1 : ib0;                   \
        D0 = tap_ == 2 ? d20 : tap_ == 1 ? d10 : d00;                         \
        D1 = tap_ == 2 ? d21 : tap_ == 1 ? d11 : d01;                         \
        const float* xp_ = xb + (size_t)c0_ * L_ + ib_;                       \
        _Pragma("unroll")                                                     \
        for (int j = 0; j < 8; ++j) {                                         \
            G0[j] = xp_[(size_t)j * L_];                                      \
            G1[j] = xp_[(size_t)j * L_ + 1];                                  \
        }                                                                     \
    }
    #define PACK(NBUF, SL, G0, G1, D0, D1) {                                  \
        union { unsigned short us[8]; i32x4 v; } ph_;                         \
        _Pragma("unroll")                                                     \
        for (int e = 0; e < 8; ++e)                                           \
            ph_.us[e] = bf16_rne(fmaf(G1[e], D1, G0[e] * D0));                \
        sS[NBUF][SL][ls] = ph_.v;                                             \
    }

    aP0 = *(const bf16x8*)(WA);
    aP1 = *(const bf16x8*)(WA + 16);
    aP2 = *(const bf16x8*)(WA + 32);
    aP3 = *(const bf16x8*)(WA + 48);
    GATHER(0, su,     g0a, g1a, dA0, dA1)
    GATHER(0, su + 4, g0b, g1b, dB0, dB1)
    PACK(0, su,     g0a, g1a, dA0, dA1)
    PACK(0, su + 4, g0b, g1b, dB0, dB1)
    __syncthreads();

    #pragma unroll
    for (int ch = 0; ch < 12; ++ch) {
        const int buf = ch & 1;

        if (ch < 11) {
            const unsigned short* wn = WA + (ch + 1) * 64;
            aQ0 = *(const bf16x8*)(wn);
            aQ1 = *(const bf16x8*)(wn + 16);
            aQ2 = *(const bf16x8*)(wn + 32);
            aQ3 = *(const bf16x8*)(wn + 48);
            GATHER(ch + 1, su,     g0a, g1a, dA0, dA1)
            GATHER(ch + 1, su + 4, g0b, g1b, dB0, dB1)
        }
        __builtin_amdgcn_sched_barrier(0);

        #define KS_STEP(ks, AP) {                                            \
            const i32x4* bp = &sS[buf][(ks) * 2 + q][l31];                   \
            bf16x8 b0 = *(const bf16x8*)(bp);                                \
            bf16x8 b1 = *(const bf16x8*)(bp + 32);                           \
            bf16x8 b2 = *(const bf16x8*)(bp + 64);                           \
            bf16x8 b3 = *(const bf16x8*)(bp + 96);                           \
            __builtin_amdgcn_s_setprio(1);                                   \
            acc0 = __builtin_amdgcn_mfma_f32_32x32x16_bf16(AP, b0, acc0, 0, 0, 0); \
            acc1 = __builtin_amdgcn_mfma_f32_32x32x16_bf16(AP, b1, acc1, 0, 0, 0); \
            acc2 = __builtin_amdgcn_mfma_f32_32x32x16_bf16(AP, b2, acc2, 0, 0, 0); \
            acc3 = __builtin_amdgcn_mfma_f32_32x32x16_bf16(AP, b3, acc3, 0, 0, 0); \
            __builtin_amdgcn_s_setprio(0);                                   \
        }
        KS_STEP(0, aP0)
        KS_STEP(1, aP1)
        KS_STEP(2, aP2)
        KS_STEP(3, aP3)
        #undef KS_STEP
        __builtin_amdgcn_sched_barrier(0);

        if (ch < 11) {
            PACK(buf ^ 1, su,     g0a, g1a, dA0, dA1)
            PACK(buf ^ 1, su + 4, g0b, g1b, dB0, dB1)
            aP0 = aQ0; aP1 = aQ1; aP2 = aQ2; aP3 = aQ3;
        }
        __syncthreads();
    }
    #undef GATHER
    #undef PACK

    #pragma unroll
    for (int reg = 0; reg < 16; ++reg) {
        int rr = (reg & 3) + 8 * (reg >> 2) + 4 * q;
        int o  = wv * 32 + rr;
        float bv = bias[o];
        float* op = out + ((size_t)b * 256 + o) * L_ + l0 + l31;
        op[0]  = acc0[reg] + bv;
        op[32] = acc1[reg] + bv;
        op[64] = acc2[reg] + bv;
        op[96] = acc3[reg] + bv;
    }
}

// ---------------------------------------------------------------------------
extern "C" void kernel_launch(void* const* d_in, const int* in_sizes, int n_in,
                              void* d_out, int out_size, void* d_ws, size_t ws_size,
                              hipStream_t stream) {
    const float* x      = (const float*)d_in[0];
    const float* weight = (const float*)d_in[1];
    const float* bias   = (const float*)d_in[2];
    const float* w1     = (const float*)d_in[3];
    const float* b1     = (const float*)d_in[4];
    const float* w2     = (const float*)d_in[5];
    const float* b2     = (const float*)d_in[6];
    float* out = (float*)d_out;

    const size_t COEF_B = (size_t)B_ * 3 * L_ * sizeof(float4);   // 1.5 MB
    char* ws = (char*)d_ws;
    float4*         coef = (float4*)ws;
    unsigned short* Wb   = (unsigned short*)(ws + COEF_B);        // 384 KB

    k_offsets<<<B_ * (L_ / 64), 256, 0, stream>>>(x, w1, b1, w2, b2,
                                                  weight, Wb, coef);
    k_conv<<<B_ * (L_ / 128), 512, 0, stream>>>(x, Wb, bias, coef, out);
}

// Round 23
// 67.896 us; speedup vs baseline: 2.9400x; 1.0010x over previous
//
#include <hip/hip_runtime.h>
#include <hip/hip_bf16.h>
#include <math.h>

#define B_    8
#define C_    256
#define L_    4096
#define OCH_  256

typedef __attribute__((ext_vector_type(8)))  short bf16x8;
typedef __attribute__((ext_vector_type(16))) float f32x16;
typedef __attribute__((ext_vector_type(4)))  int   i32x4;

static __device__ __forceinline__ unsigned short bf16_rne(float f) {
    unsigned u = __float_as_uint(f);
    unsigned r = u + 0x7FFFu + ((u >> 16) & 1u);
    return (unsigned short)(r >> 16);
}

static __device__ __forceinline__ void gload_lds16(const void* g, void* l) {
    __builtin_amdgcn_global_load_lds(
        (const __attribute__((address_space(1))) unsigned int*)g,
        (__attribute__((address_space(3))) unsigned int*)l, 16, 0, 0);
}

// ---------------------------------------------------------------------------
// K1: offset network + fused weight split — LDS-staged x tile (R21-proven,
// byte-identical). c-loop unroll 8 (full unroll spills: R20).
// coef[(b*3+t)*L + l] = { d0, d1, bits(i0f2), 0 }.
// ---------------------------------------------------------------------------
__global__ __launch_bounds__(256) void k_offsets(
        const float* __restrict__ x,
        const float* __restrict__ w1, const float* __restrict__ b1,
        const float* __restrict__ w2, const float* __restrict__ b2,
        const float* __restrict__ W,  unsigned short* __restrict__ Wb,
        float4* __restrict__ coef) {
    __shared__ float sX[C_ * 64];                    // 64 KB  [c][l]
    __shared__ float sOm[64][37];                    // 9.25 KB
    int tid  = threadIdx.x;
    int blk  = blockIdx.x;

    int b  = blk & 7;                                // XCD affinity
    int l0 = (blk >> 3) << 6;
    const float* xb = x + (size_t)b * C_ * L_;

    // ---- stage x tile: 16 rounds x 4KB, all coalesced ----
    {
        int rowi = tid >> 4;                         // 0..15
        int co   = (tid & 15) * 4;                   // element offset in row
        #pragma unroll
        for (int r = 0; r < 16; ++r) {
            int row = r * 16 + rowi;
            gload_lds16(xb + (size_t)row * L_ + l0 + co, &sX[row * 64 + co]);
        }
    }

    // ---- fused weight split: W[o][c][k] -> Wb[o][k*256+c], 384/block ----
    {
        int i = blk * 384 + tid;                     // o*768 + c*3 + k
        int k = i % 3;
        int c = (i / 3) & 255;
        int o = i / 768;
        Wb[o * 768 + k * 256 + c] = bf16_rne(W[i]);
        if (tid < 128) {
            int i2 = blk * 384 + 256 + tid;
            int k2 = i2 % 3;
            int c2 = (i2 / 3) & 255;
            int o2 = i2 / 768;
            Wb[o2 * 768 + k2 * 256 + c2] = bf16_rne(W[i2]);
        }
    }
    __syncthreads();                                 // drains vmcnt + barrier

    int l = tid & 63;
    int g = tid >> 6;

    // ---- layer 1: h = W1_g · x[g*64 .. +63][l] + b1 (LDS reads, unroll 8) ----
    const float* w1g = w1 + (g * 16) * 64;
    const float* xs  = sX + (g * 64) * 64 + l;
    float h[16];
    #pragma unroll
    for (int o = 0; o < 16; ++o) h[o] = b1[g * 16 + o];
    #pragma unroll 8
    for (int c = 0; c < 64; ++c) {
        float xv = xs[c * 64];
        #pragma unroll
        for (int o = 0; o < 16; ++o) h[o] = fmaf(xv, w1g[o * 64 + c], h[o]);
    }

    // ---- layer 2: om9 = W2_g · gelu(h) + b2 ----
    float om9[9];
    #pragma unroll
    for (int j = 0; j < 9; ++j) om9[j] = b2[g * 9 + j];
    #pragma unroll
    for (int o = 0; o < 16; ++o) {
        float a  = h[o];
        float hv = 0.5f * a * (1.0f + erff(a * 0.70710678118654752f));
        const float* w2p = w2 + g * 144 + o;         // w2[g][j][o]
        #pragma unroll
        for (int j = 0; j < 9; ++j) om9[j] = fmaf(hv, w2p[j * 16], om9[j]);
    }
    #pragma unroll
    for (int j = 0; j < 9; ++j) sOm[l][g * 9 + j] = om9[j];
    __syncthreads();
    if (tid >= 64) return;

    // ---- softmax over channels 3..35, window-form coef ----
    float om[36];
    #pragma unroll
    for (int j = 0; j < 36; ++j) om[j] = sOm[tid][j];
    om[1] = 0.0f; om[3] = 0.0f; om[5] = 0.0f;
    float m = om[3];
    #pragma unroll
    for (int j = 4; j < 36; ++j) m = fmaxf(m, om[j]);
    float ssum = 0.0f;
    #pragma unroll
    for (int j = 3; j < 36; ++j) ssum += expf(om[j] - m);
    float inv = 1.0f / ssum;

    int lpos = l0 + tid;
    float base = -1.0f + 2.0f * (float)lpos / (float)(L_ - 1);
    #pragma unroll
    for (int t = 0; t < 3; ++t) {
        float mod  = expf(om[3 + t] - m) * inv;
        float off  = om[2 * t] * (2.0f / (float)L_);
        float grid = base + (-0.5f + 0.5f * (float)t) + off;
        float pp   = (grid + 1.0f) * 0.5f * (float)(L_ - 1);
        float fp   = floorf(pp);
        int i0 = (int)fp, i1 = i0 + 1;
        float w = pp - fp;
        float c0 = (i0 >= 0 && i0 < L_) ? (1.0f - w) * mod : 0.0f;
        float c1 = (i1 >= 0 && i1 < L_) ? w * mod : 0.0f;
        int i0c  = min(max(i0, 0), L_ - 1);
        int i1c  = min(max(i1, 0), L_ - 1);
        int i0f2 = min(max(i0, 0), L_ - 2);
        float d0 = (i0c == i0f2     ? c0 : 0.0f) + (i1c == i0f2     ? c1 : 0.0f);
        float d1 = (i0c == i0f2 + 1 ? c0 : 0.0f) + (i1c == i0f2 + 1 ? c1 : 0.0f);
        coef[((size_t)b * 3 + t) * L_ + lpos] =
            make_float4(d0, d1, __int_as_float(i0f2), 0.0f);
    }
}

// ---------------------------------------------------------------------------
// K2: FUSED sample + 1-pass bf16 MFMA GEMM (R15/R19/R21-proven, byte-identical).
// Tile 256o x 128l, grid 256. Per chunk: issue A(ch+1)+G(ch+1) ->
// 16 MFMAs (gathers fly underneath) -> pack -> ds_write buf^1 -> sync.
// ---------------------------------------------------------------------------
__global__ __launch_bounds__(512, 2) void k_conv(
        const float* __restrict__ x,
        const unsigned short* __restrict__ Wb,
        const float* __restrict__ bias,
        const float4* __restrict__ coef,
        float* __restrict__ out) {
    __shared__ i32x4 sS[2][8][128];                  // 32 KB

    const int tid  = threadIdx.x;
    const int lane = tid & 63;
    const int wv   = tid >> 6;                       // 0..7
    const int blk  = blockIdx.x;
    const int b    = blk & 7;                        // XCD affinity
    const int lt   = blk >> 3;                       // 0..31
    const int l0   = lt * 128;
    const int q    = lane >> 5;
    const int l31  = lane & 31;
    const int ls   = tid & 127;                      // staging column
    const int su   = tid >> 7;                       // staging sub-slot 0..3

    const float* xb = x + (size_t)b * (C_ * L_);

    float4 cf0 = coef[((size_t)b * 3 + 0) * L_ + l0 + ls];
    float4 cf1 = coef[((size_t)b * 3 + 1) * L_ + l0 + ls];
    float4 cf2 = coef[((size_t)b * 3 + 2) * L_ + l0 + ls];
    const int   ib0 = __float_as_int(cf0.z), ib1 = __float_as_int(cf1.z), ib2 = __float_as_int(cf2.z);
    const float d00 = cf0.x, d01 = cf0.y;
    const float d10 = cf1.x, d11 = cf1.y;
    const float d20 = cf2.x, d21 = cf2.y;

    const unsigned short* WA = Wb + (size_t)(wv * 32 + l31) * 768 + q * 8;

    f32x16 acc0, acc1, acc2, acc3;
    #pragma unroll
    for (int i = 0; i < 16; ++i) { acc0[i] = 0.f; acc1[i] = 0.f; acc2[i] = 0.f; acc3[i] = 0.f; }

    bf16x8 aP0, aP1, aP2, aP3, aQ0, aQ1, aQ2, aQ3;
    float g0a[8], g1a[8], g0b[8], g1b[8];
    float dA0, dA1, dB0, dB1;

    #define GATHER(CH, SL, G0, G1, D0, D1) {                                  \
        int s_   = (CH) * 8 + (SL);                                           \
        int tap_ = s_ >> 5;                                                   \
        int c0_  = s_ * 8 - tap_ * 256;                                       \
        int ib_  = tap_ == 2 ? ib2 : tap_ == 1 ? ib1 : ib0;                   \
        D0 = tap_ == 2 ? d20 : tap_ == 1 ? d10 : d00;                         \
        D1 = tap_ == 2 ? d21 : tap_ == 1 ? d11 : d01;                         \
        const float* xp_ = xb + (size_t)c0_ * L_ + ib_;                       \
        _Pragma("unroll")                                                     \
        for (int j = 0; j < 8; ++j) {                                         \
            G0[j] = xp_[(size_t)j * L_];                                      \
            G1[j] = xp_[(size_t)j * L_ + 1];                                  \
        }                                                                     \
    }
    #define PACK(NBUF, SL, G0, G1, D0, D1) {                                  \
        union { unsigned short us[8]; i32x4 v; } ph_;                         \
        _Pragma("unroll")                                                     \
        for (int e = 0; e < 8; ++e)                                           \
            ph_.us[e] = bf16_rne(fmaf(G1[e], D1, G0[e] * D0));                \
        sS[NBUF][SL][ls] = ph_.v;                                             \
    }

    aP0 = *(const bf16x8*)(WA);
    aP1 = *(const bf16x8*)(WA + 16);
    aP2 = *(const bf16x8*)(WA + 32);
    aP3 = *(const bf16x8*)(WA + 48);
    GATHER(0, su,     g0a, g1a, dA0, dA1)
    GATHER(0, su + 4, g0b, g1b, dB0, dB1)
    PACK(0, su,     g0a, g1a, dA0, dA1)
    PACK(0, su + 4, g0b, g1b, dB0, dB1)
    __syncthreads();

    #pragma unroll
    for (int ch = 0; ch < 12; ++ch) {
        const int buf = ch & 1;

        if (ch < 11) {
            const unsigned short* wn = WA + (ch + 1) * 64;
            aQ0 = *(const bf16x8*)(wn);
            aQ1 = *(const bf16x8*)(wn + 16);
            aQ2 = *(const bf16x8*)(wn + 32);
            aQ3 = *(const bf16x8*)(wn + 48);
            GATHER(ch + 1, su,     g0a, g1a, dA0, dA1)
            GATHER(ch + 1, su + 4, g0b, g1b, dB0, dB1)
        }
        __builtin_amdgcn_sched_barrier(0);

        #define KS_STEP(ks, AP) {                                            \
            const i32x4* bp = &sS[buf][(ks) * 2 + q][l31];                   \
            bf16x8 b0 = *(const bf16x8*)(bp);                                \
            bf16x8 b1 = *(const bf16x8*)(bp + 32);                           \
            bf16x8 b2 = *(const bf16x8*)(bp + 64);                           \
            bf16x8 b3 = *(const bf16x8*)(bp + 96);                           \
            __builtin_amdgcn_s_setprio(1);                                   \
            acc0 = __builtin_amdgcn_mfma_f32_32x32x16_bf16(AP, b0, acc0, 0, 0, 0); \
            acc1 = __builtin_amdgcn_mfma_f32_32x32x16_bf16(AP, b1, acc1, 0, 0, 0); \
            acc2 = __builtin_amdgcn_mfma_f32_32x32x16_bf16(AP, b2, acc2, 0, 0, 0); \
            acc3 = __builtin_amdgcn_mfma_f32_32x32x16_bf16(AP, b3, acc3, 0, 0, 0); \
            __builtin_amdgcn_s_setprio(0);                                   \
        }
        KS_STEP(0, aP0)
        KS_STEP(1, aP1)
        KS_STEP(2, aP2)
        KS_STEP(3, aP3)
        #undef KS_STEP
        __builtin_amdgcn_sched_barrier(0);

        if (ch < 11) {
            PACK(buf ^ 1, su,     g0a, g1a, dA0, dA1)
            PACK(buf ^ 1, su + 4, g0b, g1b, dB0, dB1)
            aP0 = aQ0; aP1 = aQ1; aP2 = aQ2; aP3 = aQ3;
        }
        __syncthreads();
    }
    #undef GATHER
    #undef PACK

    #pragma unroll
    for (int reg = 0; reg < 16; ++reg) {
        int rr = (reg & 3) + 8 * (reg >> 2) + 4 * q;
        int o  = wv * 32 + rr;
        float bv = bias[o];
        float* op = out + ((size_t)b * 256 + o) * L_ + l0 + l31;
        op[0]  = acc0[reg] + bv;
        op[32] = acc1[reg] + bv;
        op[64] = acc2[reg] + bv;
        op[96] = acc3[reg] + bv;
    }
}

// ---------------------------------------------------------------------------
extern "C" void kernel_launch(void* const* d_in, const int* in_sizes, int n_in,
                              void* d_out, int out_size, void* d_ws, size_t ws_size,
                              hipStream_t stream) {
    const float* x      = (const float*)d_in[0];
    const float* weight = (const float*)d_in[1];
    const float* bias   = (const float*)d_in[2];
    const float* w1     = (const float*)d_in[3];
    const float* b1     = (const float*)d_in[4];
    const float* w2     = (const float*)d_in[5];
    const float* b2     = (const float*)d_in[6];
    float* out = (float*)d_out;

    const size_t COEF_B = (size_t)B_ * 3 * L_ * sizeof(float4);   // 1.5 MB
    char* ws = (char*)d_ws;
    float4*         coef = (float4*)ws;
    unsigned short* Wb   = (unsigned short*)(ws + COEF_B);        // 384 KB

    k_offsets<<<B_ * (L_ / 64), 256, 0, stream>>>(x, w1, b1, w2, b2,
                                                  weight, Wb, coef);
    k_conv<<<B_ * (L_ / 128), 512, 0, stream>>>(x, Wb, bias, coef, out);
}

// Round 25
// 67.867 us; speedup vs baseline: 2.9413x; 1.0004x over previous
//
#include <hip/hip_runtime.h>
#include <hip/hip_bf16.h>
#include <math.h>

#define B_    8
#define C_    256
#define L_    4096
#define OCH_  256

typedef __attribute__((ext_vector_type(8)))  short bf16x8;
typedef __attribute__((ext_vector_type(16))) float f32x16;
typedef __attribute__((ext_vector_type(4)))  int   i32x4;

static __device__ __forceinline__ unsigned short bf16_rne(float f) {
    unsigned u = __float_as_uint(f);
    unsigned r = u + 0x7FFFu + ((u >> 16) & 1u);
    return (unsigned short)(r >> 16);
}

static __device__ __forceinline__ void gload_lds16(const void* g, void* l) {
    __builtin_amdgcn_global_load_lds(
        (const __attribute__((address_space(1))) unsigned int*)g,
        (__attribute__((address_space(3))) unsigned int*)l, 16, 0, 0);
}

// ---------------------------------------------------------------------------
// K1: offset network + fused weight split — LDS-staged x tile (R21/R23-proven,
// byte-identical). c-loop unroll 8 (full unroll spills: R20).
// coef[(b*3+t)*L + l] = { d0, d1, bits(i0f2), 0 }.
// ---------------------------------------------------------------------------
__global__ __launch_bounds__(256) void k_offsets(
        const float* __restrict__ x,
        const float* __restrict__ w1, const float* __restrict__ b1,
        const float* __restrict__ w2, const float* __restrict__ b2,
        const float* __restrict__ W,  unsigned short* __restrict__ Wb,
        float4* __restrict__ coef) {
    __shared__ float sX[C_ * 64];                    // 64 KB  [c][l]
    __shared__ float sOm[64][37];                    // 9.25 KB
    int tid  = threadIdx.x;
    int blk  = blockIdx.x;

    int b  = blk & 7;                                // XCD affinity
    int l0 = (blk >> 3) << 6;
    const float* xb = x + (size_t)b * C_ * L_;

    // ---- stage x tile: 16 rounds x 4KB, all coalesced ----
    {
        int rowi = tid >> 4;                         // 0..15
        int co   = (tid & 15) * 4;                   // element offset in row
        #pragma unroll
        for (int r = 0; r < 16; ++r) {
            int row = r * 16 + rowi;
            gload_lds16(xb + (size_t)row * L_ + l0 + co, &sX[row * 64 + co]);
        }
    }

    // ---- fused weight split: W[o][c][k] -> Wb[o][k*256+c], 384/block ----
    {
        int i = blk * 384 + tid;                     // o*768 + c*3 + k
        int k = i % 3;
        int c = (i / 3) & 255;
        int o = i / 768;
        Wb[o * 768 + k * 256 + c] = bf16_rne(W[i]);
        if (tid < 128) {
            int i2 = blk * 384 + 256 + tid;
            int k2 = i2 % 3;
            int c2 = (i2 / 3) & 255;
            int o2 = i2 / 768;
            Wb[o2 * 768 + k2 * 256 + c2] = bf16_rne(W[i2]);
        }
    }
    __syncthreads();                                 // drains vmcnt + barrier

    int l = tid & 63;
    int g = tid >> 6;

    // ---- layer 1: h = W1_g · x[g*64 .. +63][l] + b1 (LDS reads, unroll 8) ----
    const float* w1g = w1 + (g * 16) * 64;
    const float* xs  = sX + (g * 64) * 64 + l;
    float h[16];
    #pragma unroll
    for (int o = 0; o < 16; ++o) h[o] = b1[g * 16 + o];
    #pragma unroll 8
    for (int c = 0; c < 64; ++c) {
        float xv = xs[c * 64];
        #pragma unroll
        for (int o = 0; o < 16; ++o) h[o] = fmaf(xv, w1g[o * 64 + c], h[o]);
    }

    // ---- layer 2: om9 = W2_g · gelu(h) + b2 ----
    float om9[9];
    #pragma unroll
    for (int j = 0; j < 9; ++j) om9[j] = b2[g * 9 + j];
    #pragma unroll
    for (int o = 0; o < 16; ++o) {
        float a  = h[o];
        float hv = 0.5f * a * (1.0f + erff(a * 0.70710678118654752f));
        const float* w2p = w2 + g * 144 + o;         // w2[g][j][o]
        #pragma unroll
        for (int j = 0; j < 9; ++j) om9[j] = fmaf(hv, w2p[j * 16], om9[j]);
    }
    #pragma unroll
    for (int j = 0; j < 9; ++j) sOm[l][g * 9 + j] = om9[j];
    __syncthreads();
    if (tid >= 64) return;

    // ---- softmax over channels 3..35, window-form coef ----
    float om[36];
    #pragma unroll
    for (int j = 0; j < 36; ++j) om[j] = sOm[tid][j];
    om[1] = 0.0f; om[3] = 0.0f; om[5] = 0.0f;
    float m = om[3];
    #pragma unroll
    for (int j = 4; j < 36; ++j) m = fmaxf(m, om[j]);
    float ssum = 0.0f;
    #pragma unroll
    for (int j = 3; j < 36; ++j) ssum += expf(om[j] - m);
    float inv = 1.0f / ssum;

    int lpos = l0 + tid;
    float base = -1.0f + 2.0f * (float)lpos / (float)(L_ - 1);
    #pragma unroll
    for (int t = 0; t < 3; ++t) {
        float mod  = expf(om[3 + t] - m) * inv;
        float off  = om[2 * t] * (2.0f / (float)L_);
        float grid = base + (-0.5f + 0.5f * (float)t) + off;
        float pp   = (grid + 1.0f) * 0.5f * (float)(L_ - 1);
        float fp   = floorf(pp);
        int i0 = (int)fp, i1 = i0 + 1;
        float w = pp - fp;
        float c0 = (i0 >= 0 && i0 < L_) ? (1.0f - w) * mod : 0.0f;
        float c1 = (i1 >= 0 && i1 < L_) ? w * mod : 0.0f;
        int i0c  = min(max(i0, 0), L_ - 1);
        int i1c  = min(max(i1, 0), L_ - 1);
        int i0f2 = min(max(i0, 0), L_ - 2);
        float d0 = (i0c == i0f2     ? c0 : 0.0f) + (i1c == i0f2     ? c1 : 0.0f);
        float d1 = (i0c == i0f2 + 1 ? c0 : 0.0f) + (i1c == i0f2 + 1 ? c1 : 0.0f);
        coef[((size_t)b * 3 + t) * L_ + lpos] =
            make_float4(d0, d1, __int_as_float(i0f2), 0.0f);
    }
}

// ---------------------------------------------------------------------------
// K2: FUSED sample + 1-pass bf16 MFMA GEMM (R15/R19/R21/R23-proven,
// byte-identical). Tile 256o x 128l, grid 256. Per chunk: issue
// A(ch+1)+G(ch+1) -> 16 MFMAs (gathers fly underneath) -> pack ->
// ds_write buf^1 -> sync.
// ---------------------------------------------------------------------------
__global__ __launch_bounds__(512, 2) void k_conv(
        const float* __restrict__ x,
        const unsigned short* __restrict__ Wb,
        const float* __restrict__ bias,
        const float4* __restrict__ coef,
        float* __restrict__ out) {
    __shared__ i32x4 sS[2][8][128];                  // 32 KB

    const int tid  = threadIdx.x;
    const int lane = tid & 63;
    const int wv   = tid >> 6;                       // 0..7
    const int blk  = blockIdx.x;
    const int b    = blk & 7;                        // XCD affinity
    const int lt   = blk >> 3;                       // 0..31
    const int l0   = lt * 128;
    const int q    = lane >> 5;
    const int l31  = lane & 31;
    const int ls   = tid & 127;                      // staging column
    const int su   = tid >> 7;                       // staging sub-slot 0..3

    const float* xb = x + (size_t)b * (C_ * L_);

    float4 cf0 = coef[((size_t)b * 3 + 0) * L_ + l0 + ls];
    float4 cf1 = coef[((size_t)b * 3 + 1) * L_ + l0 + ls];
    float4 cf2 = coef[((size_t)b * 3 + 2) * L_ + l0 + ls];
    const int   ib0 = __float_as_int(cf0.z), ib1 = __float_as_int(cf1.z), ib2 = __float_as_int(cf2.z);
    const float d00 = cf0.x, d01 = cf0.y;
    const float d10 = cf1.x, d11 = cf1.y;
    const float d20 = cf2.x, d21 = cf2.y;

    const unsigned short* WA = Wb + (size_t)(wv * 32 + l31) * 768 + q * 8;

    f32x16 acc0, acc1, acc2, acc3;
    #pragma unroll
    for (int i = 0; i < 16; ++i) { acc0[i] = 0.f; acc1[i] = 0.f; acc2[i] = 0.f; acc3[i] = 0.f; }

    bf16x8 aP0, aP1, aP2, aP3, aQ0, aQ1, aQ2, aQ3;
    float g0a[8], g1a[8], g0b[8], g1b[8];
    float dA0, dA1, dB0, dB1;

    #define GATHER(CH, SL, G0, G1, D0, D1) {                                  \
        int s_   = (CH) * 8 + (SL);                                           \
        int tap_ = s_ >> 5;                                                   \
        int c0_  = s_ * 8 - tap_ * 256;                                       \
        int ib_  = tap_ == 2 ? ib2 : tap_ == 1 ? ib1 : ib0;                   \
        D0 = tap_ == 2 ? d20 : tap_ == 1 ? d10 : d00;                         \
        D1 = tap_ == 2 ? d21 : tap_ == 1 ? d11 : d01;                         \
        const float* xp_ = xb + (size_t)c0_ * L_ + ib_;                       \
        _Pragma("unroll")                                                     \
        for (int j = 0; j < 8; ++j) {                                         \
            G0[j] = xp_[(size_t)j * L_];                                      \
            G1[j] = xp_[(size_t)j * L_ + 1];                                  \
        }                                                                     \
    }
    #define PACK(NBUF, SL, G0, G1, D0, D1) {                                  \
        union { unsigned short us[8]; i32x4 v; } ph_;                         \
        _Pragma("unroll")                                                     \
        for (int e = 0; e < 8; ++e)                                           \
            ph_.us[e] = bf16_rne(fmaf(G1[e], D1, G0[e] * D0));                \
        sS[NBUF][SL][ls] = ph_.v;                                             \
    }

    aP0 = *(const bf16x8*)(WA);
    aP1 = *(const bf16x8*)(WA + 16);
    aP2 = *(const bf16x8*)(WA + 32);
    aP3 = *(const bf16x8*)(WA + 48);
    GATHER(0, su,     g0a, g1a, dA0, dA1)
    GATHER(0, su + 4, g0b, g1b, dB0, dB1)
    PACK(0, su,     g0a, g1a, dA0, dA1)
    PACK(0, su + 4, g0b, g1b, dB0, dB1)
    __syncthreads();

    #pragma unroll
    for (int ch = 0; ch < 12; ++ch) {
        const int buf = ch & 1;

        if (ch < 11) {
            const unsigned short* wn = WA + (ch + 1) * 64;
            aQ0 = *(const bf16x8*)(wn);
            aQ1 = *(const bf16x8*)(wn + 16);
            aQ2 = *(const bf16x8*)(wn + 32);
            aQ3 = *(const bf16x8*)(wn + 48);
            GATHER(ch + 1, su,     g0a, g1a, dA0, dA1)
            GATHER(ch + 1, su + 4, g0b, g1b, dB0, dB1)
        }
        __builtin_amdgcn_sched_barrier(0);

        #define KS_STEP(ks, AP) {                                            \
            const i32x4* bp = &sS[buf][(ks) * 2 + q][l31];                   \
            bf16x8 b0 = *(const bf16x8*)(bp);                                \
            bf16x8 b1 = *(const bf16x8*)(bp + 32);                           \
            bf16x8 b2 = *(const bf16x8*)(bp + 64);                           \
            bf16x8 b3 = *(const bf16x8*)(bp + 96);                           \
            __builtin_amdgcn_s_setprio(1);                                   \
            acc0 = __builtin_amdgcn_mfma_f32_32x32x16_bf16(AP, b0, acc0, 0, 0, 0); \
            acc1 = __builtin_amdgcn_mfma_f32_32x32x16_bf16(AP, b1, acc1, 0, 0, 0); \
            acc2 = __builtin_amdgcn_mfma_f32_32x32x16_bf16(AP, b2, acc2, 0, 0, 0); \
            acc3 = __builtin_amdgcn_mfma_f32_32x32x16_bf16(AP, b3, acc3, 0, 0, 0); \
            __builtin_amdgcn_s_setprio(0);                                   \
        }
        KS_STEP(0, aP0)
        KS_STEP(1, aP1)
        KS_STEP(2, aP2)
        KS_STEP(3, aP3)
        #undef KS_STEP
        __builtin_amdgcn_sched_barrier(0);

        if (ch < 11) {
            PACK(buf ^ 1, su,     g0a, g1a, dA0, dA1)
            PACK(buf ^ 1, su + 4, g0b, g1b, dB0, dB1)
            aP0 = aQ0; aP1 = aQ1; aP2 = aQ2; aP3 = aQ3;
        }
        __syncthreads();
    }
    #undef GATHER
    #undef PACK

    #pragma unroll
    for (int reg = 0; reg < 16; ++reg) {
        int rr = (reg & 3) + 8 * (reg >> 2) + 4 * q;
        int o  = wv * 32 + rr;
        float bv = bias[o];
        float* op = out + ((size_t)b * 256 + o) * L_ + l0 + l31;
        op[0]  = acc0[reg] + bv;
        op[32] = acc1[reg] + bv;
        op[64] = acc2[reg] + bv;
        op[96] = acc3[reg] + bv;
    }
}

// ---------------------------------------------------------------------------
extern "C" void kernel_launch(void* const* d_in, const int* in_sizes, int n_in,
                              void* d_out, int out_size, void* d_ws, size_t ws_size,
                              hipStream_t stream) {
    const float* x      = (const float*)d_in[0];
    const float* weight = (const float*)d_in[1];
    const float* bias   = (const float*)d_in[2];
    const float* w1     = (const float*)d_in[3];
    const float* b1     = (const float*)d_in[4];
    const float* w2     = (const float*)d_in[5];
    const float* b2     = (const float*)d_in[6];
    float* out = (float*)d_out;

    const size_t COEF_B = (size_t)B_ * 3 * L_ * sizeof(float4);   // 1.5 MB
    char* ws = (char*)d_ws;
    float4*         coef = (float4*)ws;
    unsigned short* Wb   = (unsigned short*)(ws + COEF_B);        // 384 KB

    k_offsets<<<B_ * (L_ / 64), 256, 0, stream>>>(x, w1, b1, w2, b2,
                                                  weight, Wb, coef);
    k_conv<<<B_ * (L_ / 128), 512, 0, stream>>>(x, Wb, bias, coef, out);
}